// Round 1
// baseline (119.064 us; speedup 1.0000x reference)
//
#include <hip/hip_runtime.h>
#include <math.h>

// Problem constants (from reference): NG=4, N=6, NFG=8, NFR=256, NACT=5, B=32768
// sim factorization: sim[g,n,m] = (f_n^T M_g f_m + U_g.f_n + V_g.f_m + C_g)/16
//   M_g[f1][f2] = sum_r Wtheta[g,r,f1]*Wphi[g,r,f2]   (8x8)
//   U_g[f]      = sum_r Wtheta[g,r,f]*b_phi[g,r]
//   V_g[f]      = sum_r Wphi[g,r,f]*b_theta[g,r]
//   C_g         = sum_r b_theta[g,r]*b_phi[g,r]
// ws layout (floats): M[4*64] @0, U[4*8] @256, V[4*8] @288, C[4] @320  (324 floats)

__global__ void gcn_precompute(const float* __restrict__ Wt, const float* __restrict__ bt,
                               const float* __restrict__ Wp, const float* __restrict__ bp,
                               float* __restrict__ ws) {
  const int t = threadIdx.x;  // 256 threads
  const int g = t >> 6, idx = t & 63, f1 = idx >> 3, f2 = idx & 7;
  const float* wt = Wt + g * 2048;
  const float* wp = Wp + g * 2048;
  float m = 0.0f;
#pragma unroll 8
  for (int r = 0; r < 256; ++r) m = fmaf(wt[r * 8 + f1], wp[r * 8 + f2], m);
  ws[g * 64 + f1 * 8 + f2] = m;
  if (t < 32) {
    const int gg = t >> 3, f = t & 7;
    const float* w = Wt + gg * 2048;
    const float* b = bp + gg * 256;
    float s = 0.0f;
#pragma unroll 8
    for (int r = 0; r < 256; ++r) s = fmaf(w[r * 8 + f], b[r], s);
    ws[256 + t] = s;
  } else if (t < 64) {
    const int tt = t - 32, gg = tt >> 3, f = tt & 7;
    const float* w = Wp + gg * 2048;
    const float* b = bt + gg * 256;
    float s = 0.0f;
#pragma unroll 8
    for (int r = 0; r < 256; ++r) s = fmaf(w[r * 8 + f], b[r], s);
    ws[288 + tt] = s;
  } else if (t < 68) {
    const int gg = t - 64;
    const float* a = bt + gg * 256;
    const float* b = bp + gg * 256;
    float s = 0.0f;
#pragma unroll 8
    for (int r = 0; r < 256; ++r) s = fmaf(a[r], b[r], s);
    ws[320 + gg] = s;
  }
}

__launch_bounds__(64)
__global__ void gcn_main(const float* __restrict__ bfeat, const float* __restrict__ pos,
                         const float* __restrict__ W_ext, const float* __restrict__ b_ext,
                         const float* __restrict__ W_gcn, const float* __restrict__ W_act,
                         const float* __restrict__ b_act, const float* __restrict__ ws,
                         float* __restrict__ out, int B) {
  __shared__ float sWext[64];
  __shared__ float sbext[8];
  __shared__ float sM[256];
  __shared__ float sU[32];
  __shared__ float sV[32];
  __shared__ float sC[4];
  __shared__ float sWgcn[256];   // pre-scaled by 0.25 (mean over NG=4 folded in)
  __shared__ float sWact[40];
  __shared__ float sbact[5];
  __shared__ float souts[64 * 5];

  const int tid = threadIdx.x;
  sWext[tid] = W_ext[tid];
  if (tid < 8) sbext[tid] = b_ext[tid];
#pragma unroll
  for (int i = 0; i < 4; ++i) sM[tid + i * 64] = ws[tid + i * 64];
  if (tid < 32) sU[tid] = ws[256 + tid];
  if (tid < 32) sV[tid] = ws[288 + tid];
  if (tid < 4) sC[tid] = ws[320 + tid];
#pragma unroll
  for (int i = 0; i < 4; ++i) sWgcn[tid + i * 64] = 0.25f * W_gcn[tid + i * 64];
  if (tid < 40) sWact[tid] = W_act[tid];
  if (tid < 5) sbact[tid] = b_act[tid];
  __syncthreads();

  const int b = blockIdx.x * 64 + tid;
  if (b < B) {
    // ---- load positions [6][2] ----
    float px[6], py[6];
    {
      const float4* p4 = (const float4*)(pos + (size_t)b * 12);
      float4 p0 = p4[0], p1 = p4[1], p2 = p4[2];
      px[0] = p0.x; py[0] = p0.y; px[1] = p0.z; py[1] = p0.w;
      px[2] = p1.x; py[2] = p1.y; px[3] = p1.z; py[3] = p1.w;
      px[4] = p2.x; py[4] = p2.y; px[5] = p2.z; py[5] = p2.w;
    }

    // ---- load features [6][8] into gacc (doubles as residual accumulator) ----
    float gacc[6][8];
    {
      const float4* f4 = (const float4*)(bfeat + (size_t)b * 48);
#pragma unroll
      for (int i = 0; i < 12; ++i) {
        float4 v = f4[i];
        const int n = i >> 1, base = (i & 1) * 4;
        gacc[n][base + 0] = v.x; gacc[n][base + 1] = v.y;
        gacc[n][base + 2] = v.z; gacc[n][base + 3] = v.w;
      }
    }

    // ---- position mask: replicate numpy fp32 rounding EXACTLY (no fma contraction) ----
    // d2 = (r_n - 2*dot) + r_m ; dist = sqrtf(d2) [IEEE]; mask = dist > 4.0
    float rr[6];
#pragma unroll
    for (int n = 0; n < 6; ++n)
      rr[n] = __fadd_rn(__fmul_rn(px[n], px[n]), __fmul_rn(py[n], py[n]));
    unsigned long long mask = 0ull;  // bit n*6+m set => masked (-inf)
#pragma unroll
    for (int n = 0; n < 6; ++n) {
#pragma unroll
      for (int m = 0; m < 6; ++m) {
        float dot = __fadd_rn(__fmul_rn(px[n], px[m]), __fmul_rn(py[n], py[m]));
        float d2 = __fadd_rn(__fsub_rn(rr[n], __fmul_rn(2.0f, dot)), rr[m]);
        float dist = sqrtf(d2);  // NaN for diag negatives -> NaN > 4 is false (matches np)
        if (dist > 4.0f) mask |= (1ull << (n * 6 + m));
      }
    }

    // ---- feature extension: feat[n][g] = relu(bf[n].Wext_row_g + b_ext[g]) ----
    float feat[6][8];
#pragma unroll
    for (int n = 0; n < 6; ++n) {
#pragma unroll
      for (int o = 0; o < 8; ++o) {
        float s = sbext[o];
#pragma unroll
        for (int f = 0; f < 8; ++f) s = fmaf(gacc[n][f], sWext[o * 8 + f], s);
        feat[n][o] = fmaxf(s, 0.0f);
      }
    }

    // ---- per-group relation graph + GCN, accumulate 0.25*relu(...) into gacc ----
#pragma unroll 1
    for (int g = 0; g < 4; ++g) {
      const float* M = sM + g * 64;
      const float* U = sU + g * 8;
      const float* V = sV + g * 8;
      const float* Wg = sWgcn + g * 64;
      const float Cg = sC[g];

      // z[m][f1] = sum_f2 M[f1][f2]*feat[m][f2]
      float z[6][8];
#pragma unroll
      for (int m = 0; m < 6; ++m) {
#pragma unroll
        for (int f1 = 0; f1 < 8; ++f1) {
          float s = 0.0f;
#pragma unroll
          for (int f2 = 0; f2 < 8; ++f2) s = fmaf(M[f1 * 8 + f2], feat[m][f2], s);
          z[m][f1] = s;
        }
      }
      float uv[6], vv[6];
#pragma unroll
      for (int n = 0; n < 6; ++n) {
        float su = 0.0f, sv = 0.0f;
#pragma unroll
        for (int f = 0; f < 8; ++f) {
          su = fmaf(U[f], feat[n][f], su);
          sv = fmaf(V[f], feat[n][f], sv);
        }
        uv[n] = su; vv[n] = sv;
      }

#pragma unroll
      for (int n = 0; n < 6; ++n) {
        float simr[6];
        float rmax = -INFINITY;
#pragma unroll
        for (int m = 0; m < 6; ++m) {
          float s = 0.0f;
#pragma unroll
          for (int f = 0; f < 8; ++f) s = fmaf(feat[n][f], z[m][f], s);
          s = (s + uv[n] + vv[m] + Cg) * 0.0625f;
          const bool msk = (mask >> (n * 6 + m)) & 1ull;
          simr[m] = msk ? -INFINITY : s;
          rmax = fmaxf(rmax, simr[m]);
        }
        float e[6], esum = 0.0f;
#pragma unroll
        for (int m = 0; m < 6; ++m) {
          float ev = __expf(simr[m] - rmax);  // -inf -> 0
          e[m] = ev; esum += ev;
        }
        const float inv = 1.0f / esum;  // diag always unmasked -> esum >= 1
        float agg[8];
#pragma unroll
        for (int f = 0; f < 8; ++f) {
          float s = 0.0f;
#pragma unroll
          for (int m = 0; m < 6; ++m) s = fmaf(e[m] * inv, feat[m][f], s);
          agg[f] = s;
        }
#pragma unroll
        for (int o = 0; o < 8; ++o) {
          float s = 0.0f;
#pragma unroll
          for (int f = 0; f < 8; ++f) s = fmaf(Wg[o * 8 + f], agg[f], s);
          gacc[n][o] += fmaxf(s, 0.0f);  // 0.25 pre-folded into Wg; relu pos-homog
        }
      }
    }

    // ---- epilogue: states = gacc; pooled = max_n; scores = pooled @ Wact^T + bact ----
    float pooled[8];
#pragma unroll
    for (int f = 0; f < 8; ++f) {
      float mx = gacc[0][f];
#pragma unroll
      for (int n = 1; n < 6; ++n) mx = fmaxf(mx, gacc[n][f]);
      pooled[f] = mx;
    }
#pragma unroll
    for (int a = 0; a < 5; ++a) {
      float s = sbact[a];
#pragma unroll
      for (int f = 0; f < 8; ++f) s = fmaf(pooled[f], sWact[a * 8 + f], s);
      souts[tid * 5 + a] = s;
    }
  }
  __syncthreads();
  // coalesced store of this block's 320 outputs
  const long long obase = (long long)blockIdx.x * 320;
  const long long lim = (long long)B * 5;
#pragma unroll
  for (int i = 0; i < 5; ++i) {
    const long long oi = obase + tid + i * 64;
    if (oi < lim) out[oi] = souts[tid + i * 64];
  }
}

extern "C" void kernel_launch(void* const* d_in, const int* in_sizes, int n_in,
                              void* d_out, int out_size, void* d_ws, size_t ws_size,
                              hipStream_t stream) {
  const float* bfeat   = (const float*)d_in[0];
  const float* pos     = (const float*)d_in[1];
  const float* W_ext   = (const float*)d_in[2];
  const float* b_ext   = (const float*)d_in[3];
  const float* W_theta = (const float*)d_in[4];
  const float* b_theta = (const float*)d_in[5];
  const float* W_phi   = (const float*)d_in[6];
  const float* b_phi   = (const float*)d_in[7];
  const float* W_gcn   = (const float*)d_in[8];
  const float* W_act   = (const float*)d_in[9];
  const float* b_act   = (const float*)d_in[10];
  float* out = (float*)d_out;
  float* ws  = (float*)d_ws;

  const int B = in_sizes[0] / 48;  // [B,6,8]

  hipLaunchKernelGGL(gcn_precompute, dim3(1), dim3(256), 0, stream,
                     W_theta, b_theta, W_phi, b_phi, ws);
  const int grid = (B + 63) / 64;
  hipLaunchKernelGGL(gcn_main, dim3(grid), dim3(64), 0, stream,
                     bfeat, pos, W_ext, b_ext, W_gcn, W_act, b_act, ws, out, B);
}

// Round 2
// 96.804 us; speedup vs baseline: 1.2299x; 1.2299x over previous
//
#include <hip/hip_runtime.h>
#include <math.h>

// NG=4, N=6, NFG=8, NFR=256, NACT=5, B=32768
// sim factorization: sim[g,n,m] = (f_n^T M_g f_m + U_g.f_n + V_g.f_m + C_g)/16
// ws layout (floats): M[4*64] @0, U[4*8] @256, V[4*8] @288, C[4] @320

// grid=4 (one block per g), block=256. Each dot-256 split into 4 segments of 64.
__global__ void gcn_precompute(const float* __restrict__ Wt, const float* __restrict__ bt,
                               const float* __restrict__ Wp, const float* __restrict__ bp,
                               float* __restrict__ ws) {
  __shared__ float red[256];
  const int g = blockIdx.x, t = threadIdx.x;
  const float* wt = Wt + g * 2048;
  const float* wp = Wp + g * 2048;
  const float* bT = bt + g * 256;
  const float* bP = bp + g * 256;

  // --- M_g: 64 entries x 4 r-segments ---
  {
    const int task = t >> 2, seg = t & 3;
    const int f1 = task >> 3, f2 = task & 7;
    const int r0 = seg * 64;
    float s = 0.0f;
#pragma unroll 16
    for (int r = r0; r < r0 + 64; ++r) s = fmaf(wt[r * 8 + f1], wp[r * 8 + f2], s);
    red[t] = s;
  }
  __syncthreads();
  if ((t & 3) == 0) {
    const int task = t >> 2;
    ws[g * 64 + task] = red[t] + red[t + 1] + red[t + 2] + red[t + 3];
  }
  __syncthreads();

  // --- U (threads 0..31), V (32..63), C (64..67) ---
  float s2 = 0.0f;
  if (t < 32) {
    const int f = t >> 2, seg = t & 3, r0 = seg * 64;
#pragma unroll 16
    for (int r = r0; r < r0 + 64; ++r) s2 = fmaf(wt[r * 8 + f], bP[r], s2);
  } else if (t < 64) {
    const int tt = t - 32, f = tt >> 2, seg = tt & 3, r0 = seg * 64;
#pragma unroll 16
    for (int r = r0; r < r0 + 64; ++r) s2 = fmaf(wp[r * 8 + f], bT[r], s2);
  } else if (t < 68) {
    const int seg = t - 64, r0 = seg * 64;
#pragma unroll 16
    for (int r = r0; r < r0 + 64; ++r) s2 = fmaf(bT[r], bP[r], s2);
  }
  red[t] = s2;
  __syncthreads();
  if (t < 32 && (t & 3) == 0)
    ws[256 + g * 8 + (t >> 2)] = red[t] + red[t + 1] + red[t + 2] + red[t + 3];
  else if (t >= 32 && t < 64 && (t & 3) == 0)
    ws[288 + g * 8 + ((t - 32) >> 2)] = red[t] + red[t + 1] + red[t + 2] + red[t + 3];
  else if (t == 64)
    ws[320 + g] = red[64] + red[65] + red[66] + red[67];
}

// block=256: 64 elements/block, 4 lanes (one per g) per element. grid = B/64.
__launch_bounds__(256, 2)
__global__ void gcn_main(const float* __restrict__ bfeat, const float* __restrict__ pos,
                         const float* __restrict__ W_ext, const float* __restrict__ b_ext,
                         const float* __restrict__ W_gcn, const float* __restrict__ W_act,
                         const float* __restrict__ b_act, const float* __restrict__ ws,
                         float* __restrict__ out, int B) {
  // stride-65/9 padding: per-quad the 4 g-addresses land in 4 different banks
  __shared__ float sWext[64];
  __shared__ float sbext[8];
  __shared__ float sM[4 * 65];
  __shared__ float sU[4 * 9];
  __shared__ float sV[4 * 9];
  __shared__ float sC[4];
  __shared__ float sWgcn[4 * 65];  // pre-scaled by 0.25 (mean over NG folded in)
  __shared__ float sWact[40];
  __shared__ float sbact[5];

  const int tid = threadIdx.x;
  if (tid < 64) sWext[tid] = W_ext[tid];
  if (tid < 8) sbext[tid] = b_ext[tid];
  sM[(tid >> 6) * 65 + (tid & 63)] = ws[tid];
  if (tid < 32) sU[(tid >> 3) * 9 + (tid & 7)] = ws[256 + tid];
  if (tid < 32) sV[(tid >> 3) * 9 + (tid & 7)] = ws[288 + tid];
  if (tid < 4) sC[tid] = ws[320 + tid];
  sWgcn[(tid >> 6) * 65 + (tid & 63)] = 0.25f * W_gcn[tid];
  if (tid < 40) sWact[tid] = W_act[tid];
  if (tid < 5) sbact[tid] = b_act[tid];
  __syncthreads();

  const int e = blockIdx.x * 64 + (tid >> 2);  // batch element
  const int g = tid & 3;                       // relation group
  if (e >= B) return;

  // ---- load positions [6][2] (4 lanes of a quad read the same data; coalescer handles it) ----
  float px[6], py[6];
  {
    const float4* p4 = (const float4*)(pos + (size_t)e * 12);
    float4 p0 = p4[0], p1 = p4[1], p2 = p4[2];
    px[0] = p0.x; py[0] = p0.y; px[1] = p0.z; py[1] = p0.w;
    px[2] = p1.x; py[2] = p1.y; px[3] = p1.z; py[3] = p1.w;
    px[4] = p2.x; py[4] = p2.y; px[5] = p2.z; py[5] = p2.w;
  }

  // ---- load raw features [6][8] ----
  float bfr[6][8];
  {
    const float4* f4 = (const float4*)(bfeat + (size_t)e * 48);
#pragma unroll
    for (int i = 0; i < 12; ++i) {
      float4 v = f4[i];
      const int n = i >> 1, base = (i & 1) * 4;
      bfr[n][base + 0] = v.x; bfr[n][base + 1] = v.y;
      bfr[n][base + 2] = v.z; bfr[n][base + 3] = v.w;
    }
  }

  // ---- position mask: replicate numpy fp32 rounding EXACTLY (no fma contraction) ----
  float rr[6];
#pragma unroll
  for (int n = 0; n < 6; ++n)
    rr[n] = __fadd_rn(__fmul_rn(px[n], px[n]), __fmul_rn(py[n], py[n]));
  unsigned long long mask = 0ull;  // bit n*6+m set => masked (-inf)
#pragma unroll
  for (int n = 0; n < 6; ++n) {
#pragma unroll
    for (int m = 0; m < 6; ++m) {
      float dot = __fadd_rn(__fmul_rn(px[n], px[m]), __fmul_rn(py[n], py[m]));
      float d2 = __fadd_rn(__fsub_rn(rr[n], __fmul_rn(2.0f, dot)), rr[m]);
      float dist = sqrtf(d2);  // NaN on diag -> NaN > 4 false (matches np)
      if (dist > 4.0f) mask |= (1ull << (n * 6 + m));
    }
  }

  // ---- feature extension ----
  float feat[6][8];
#pragma unroll
  for (int n = 0; n < 6; ++n) {
#pragma unroll
    for (int o = 0; o < 8; ++o) {
      float s = sbext[o];
#pragma unroll
      for (int f = 0; f < 8; ++f) s = fmaf(bfr[n][f], sWext[o * 8 + f], s);
      feat[n][o] = fmaxf(s, 0.0f);
    }
  }

  // ---- con init: 0.25*bfr so the 4-lane sum contributes the residual exactly once ----
  float con[6][8];
#pragma unroll
  for (int n = 0; n < 6; ++n)
#pragma unroll
    for (int f = 0; f < 8; ++f) con[n][f] = 0.25f * bfr[n][f];

  // ---- this lane's group g ----
  const float* M = sM + g * 65;
  const float* U = sU + g * 9;
  const float* V = sV + g * 9;
  const float* Wg = sWgcn + g * 65;
  const float Cg = sC[g];

  // z[m][f1] = sum_f2 M[f1][f2]*feat[m][f2]  (f-loops outer so M loads CSE across m)
  float z[6][8];
#pragma unroll
  for (int m = 0; m < 6; ++m)
#pragma unroll
    for (int f1 = 0; f1 < 8; ++f1) z[m][f1] = 0.0f;
#pragma unroll
  for (int f1 = 0; f1 < 8; ++f1) {
#pragma unroll
    for (int f2 = 0; f2 < 8; ++f2) {
      const float Mv = M[f1 * 8 + f2];
#pragma unroll
      for (int m = 0; m < 6; ++m) z[m][f1] = fmaf(Mv, feat[m][f2], z[m][f1]);
    }
  }

  float uv[6], vv[6];
#pragma unroll
  for (int n = 0; n < 6; ++n) {
    float su = 0.0f, sv = 0.0f;
#pragma unroll
    for (int f = 0; f < 8; ++f) {
      su = fmaf(U[f], feat[n][f], su);
      sv = fmaf(V[f], feat[n][f], sv);
    }
    uv[n] = su; vv[n] = sv;
  }

  // sim + softmax -> P[6][6]
  float P[6][6];
#pragma unroll
  for (int n = 0; n < 6; ++n) {
    float simr[6];
    float rmax = -INFINITY;
#pragma unroll
    for (int m = 0; m < 6; ++m) {
      float s = 0.0f;
#pragma unroll
      for (int f = 0; f < 8; ++f) s = fmaf(feat[n][f], z[m][f], s);
      s = (s + uv[n] + vv[m] + Cg) * 0.0625f;
      const bool msk = (mask >> (n * 6 + m)) & 1ull;
      simr[m] = msk ? -INFINITY : s;
      rmax = fmaxf(rmax, simr[m]);
    }
    float e6[6], esum = 0.0f;
#pragma unroll
    for (int m = 0; m < 6; ++m) {
      float ev = __expf(simr[m] - rmax);  // -inf -> 0
      e6[m] = ev; esum += ev;
    }
    const float inv = 1.0f / esum;  // diag always unmasked
#pragma unroll
    for (int m = 0; m < 6; ++m) P[n][m] = e6[m] * inv;
  }

  // agg[n][f] = sum_m P[n][m]*feat[m][f]
  float agg[6][8];
#pragma unroll
  for (int n = 0; n < 6; ++n)
#pragma unroll
    for (int f = 0; f < 8; ++f) agg[n][f] = 0.0f;
#pragma unroll
  for (int m = 0; m < 6; ++m)
#pragma unroll
    for (int f = 0; f < 8; ++f) {
      const float fv = feat[m][f];
#pragma unroll
      for (int n = 0; n < 6; ++n) agg[n][f] = fmaf(P[n][m], fv, agg[n][f]);
    }

  // con += relu(Wg @ agg)   (Wg pre-scaled by 0.25; o,f outer so Wg loads CSE across n)
#pragma unroll
  for (int o = 0; o < 8; ++o) {
    float t6[6] = {0, 0, 0, 0, 0, 0};
#pragma unroll
    for (int f = 0; f < 8; ++f) {
      const float Wv = Wg[o * 8 + f];
#pragma unroll
      for (int n = 0; n < 6; ++n) t6[n] = fmaf(Wv, agg[n][f], t6[n]);
    }
#pragma unroll
    for (int n = 0; n < 6; ++n) con[n][o] += fmaxf(t6[n], 0.0f);
  }

  // ---- butterfly sum across the 4 g-lanes (xor 1, xor 2) ----
#pragma unroll
  for (int n = 0; n < 6; ++n)
#pragma unroll
    for (int f = 0; f < 8; ++f) {
      float v = con[n][f];
      v += __shfl_xor(v, 1);
      v += __shfl_xor(v, 2);
      con[n][f] = v;  // all 4 lanes now hold states[n][f]
    }

  // ---- epilogue (redundant on all 4 lanes) ----
  float pooled[8];
#pragma unroll
  for (int f = 0; f < 8; ++f) {
    float mx = con[0][f];
#pragma unroll
    for (int n = 1; n < 6; ++n) mx = fmaxf(mx, con[n][f]);
    pooled[f] = mx;
  }
  float sc[5];
#pragma unroll
  for (int a = 0; a < 5; ++a) {
    float s = sbact[a];
#pragma unroll
    for (int f = 0; f < 8; ++f) s = fmaf(pooled[f], sWact[a * 8 + f], s);
    sc[a] = s;
  }

  // lane g stores score g; lane 0 also stores score 4 -> near-contiguous per wave
  const size_t ob = (size_t)e * 5;
  const float myv = (g == 0) ? sc[0] : (g == 1) ? sc[1] : (g == 2) ? sc[2] : sc[3];
  out[ob + g] = myv;
  if (g == 0) out[ob + 4] = sc[4];
}

extern "C" void kernel_launch(void* const* d_in, const int* in_sizes, int n_in,
                              void* d_out, int out_size, void* d_ws, size_t ws_size,
                              hipStream_t stream) {
  const float* bfeat   = (const float*)d_in[0];
  const float* pos     = (const float*)d_in[1];
  const float* W_ext   = (const float*)d_in[2];
  const float* b_ext   = (const float*)d_in[3];
  const float* W_theta = (const float*)d_in[4];
  const float* b_theta = (const float*)d_in[5];
  const float* W_phi   = (const float*)d_in[6];
  const float* b_phi   = (const float*)d_in[7];
  const float* W_gcn   = (const float*)d_in[8];
  const float* W_act   = (const float*)d_in[9];
  const float* b_act   = (const float*)d_in[10];
  float* out = (float*)d_out;
  float* ws  = (float*)d_ws;

  const int B = in_sizes[0] / 48;  // [B,6,8]

  hipLaunchKernelGGL(gcn_precompute, dim3(4), dim3(256), 0, stream,
                     W_theta, b_theta, W_phi, b_phi, ws);
  const int grid = (B + 63) / 64;
  hipLaunchKernelGGL(gcn_main, dim3(grid), dim3(256), 0, stream,
                     bfeat, pos, W_ext, b_ext, W_gcn, W_act, b_act, ws, out, B);
}